// Round 7
// baseline (49.983 us; speedup 1.0000x reference)
//
#include <hip/hip_runtime.h>
#include <cstddef>

#define BB 16
#define NN 16385
#define NT 16384
#define CC 64
#define P1B 64   // streaming blocks per batch in phase 1 (also = 64 weight-block count)
#define P3B 128  // blocks per batch in fused phase 2+3

typedef __attribute__((ext_vector_type(4))) float f4;

// ---- Kernel 1: phase1 streaming + (blockIdx.y==BB) weight-folding M2t/M3 ----
__global__ __launch_bounds__(256) void k_p1(
    const float* __restrict__ x, const float* __restrict__ Wq,
    const float* __restrict__ Wkv, const float* __restrict__ Wp,
    float* __restrict__ mask_out, float* __restrict__ prob_out,
    float* __restrict__ po_part, float* __restrict__ ne_part,
    float* __restrict__ cnt_part,
    float* __restrict__ M2t, float* __restrict__ M3)
{
  const int b = blockIdx.y, bx = blockIdx.x;
  const int tid = threadIdx.x, lane = tid & 63, wave = tid >> 6;

  if (b == BB) {
    // weight-only precompute: block bx = c in [0,64)
    // M2t[c][j] = sum_d Wq[j][d] * Wkv[c][d]        (A = 0.125 * y . M2t)
    // M3 [c][j] = sum_d Wkv[c][64+d] * Wp[d][j]     (V' = y . M3)
    const int c = bx, j = lane, q = wave;
    float s2 = 0.f, s3 = 0.f;
    #pragma unroll
    for (int dd = 0; dd < 16; ++dd) {
      const int d = q * 16 + dd;
      s2 += Wq[j * 64 + d] * Wkv[c * 128 + d];
      s3 += Wkv[c * 128 + 64 + d] * Wp[d * 64 + j];
    }
    __shared__ float t2[4][64], t3[4][64];
    t2[q][j] = s2; t3[q][j] = s3;
    __syncthreads();
    if (q == 0) {
      M2t[c * 64 + j] = t2[0][j] + t2[1][j] + t2[2][j] + t2[3][j];
      M3 [c * 64 + j] = t3[0][j] + t3[1][j] + t3[2][j] + t3[3][j];
    }
    return;
  }

  const int g = lane & 15, t = lane >> 4, c0 = g * 4;
  const float* xb = x + (size_t)b * NN * CC;
  const f4 wt4 = *reinterpret_cast<const f4*>(xb + c0);

  float apo[4] = {0.f, 0.f, 0.f, 0.f};
  float ane4[4] = {0.f, 0.f, 0.f, 0.f};
  float cntl = 0.f;

  for (int grp = bx * 4 + wave; grp < NT / 4; grp += P1B * 4) {
    const int n0 = grp * 4;
    const f4 xv = *reinterpret_cast<const f4*>(xb + (size_t)(1 + n0 + t) * CC + c0);
    float p = xv.x * wt4.x + xv.y * wt4.y + xv.z * wt4.z + xv.w * wt4.w;
    p += __shfl_xor(p, 1);
    p += __shfl_xor(p, 2);
    p += __shfl_xor(p, 4);
    p += __shfl_xor(p, 8);
    const bool m = p > 0.f;
    const float po = m ? p : 0.f;
    const float ne = m ? 0.f : p;
    apo[0] += po * xv.x; apo[1] += po * xv.y; apo[2] += po * xv.z; apo[3] += po * xv.w;
    ane4[0] += ne * xv.x; ane4[1] += ne * xv.y; ane4[2] += ne * xv.z; ane4[3] += ne * xv.w;
    if (g == 0) {
      const int nt = n0 + t;
      mask_out[(size_t)b * NT + nt] = m ? 1.f : 0.f;
      prob_out[(size_t)b * NT + nt] = 1.f / (1.f + __expf(-p));
      if (m) cntl += 1.f;
    }
  }

  #pragma unroll
  for (int i = 0; i < 4; ++i) {
    apo[i] += __shfl_xor(apo[i], 16); apo[i] += __shfl_xor(apo[i], 32);
    ane4[i] += __shfl_xor(ane4[i], 16); ane4[i] += __shfl_xor(ane4[i], 32);
  }
  cntl += __shfl_xor(cntl, 16);
  cntl += __shfl_xor(cntl, 32);

  __shared__ float s_po[4][64], s_ne[4][64], s_cnt[4];
  if (t == 0) {
    #pragma unroll
    for (int i = 0; i < 4; ++i) { s_po[wave][c0 + i] = apo[i]; s_ne[wave][c0 + i] = ane4[i]; }
  }
  if (lane == 0) s_cnt[wave] = cntl;
  __syncthreads();
  if (wave == 0) {
    const float sp = s_po[0][lane] + s_po[1][lane] + s_po[2][lane] + s_po[3][lane];
    const float sn = s_ne[0][lane] + s_ne[1][lane] + s_ne[2][lane] + s_ne[3][lane];
    const size_t base = ((size_t)b * P1B + bx) * 64 + lane;
    po_part[base] = sp;
    ne_part[base] = sn;
    if (lane == 0) cnt_part[b * P1B + bx] = s_cnt[0] + s_cnt[1] + s_cnt[2] + s_cnt[3];
  }
}

// ---- Kernel 2: fused phase2 (redundant per block) + phase3 streaming ----
__global__ __launch_bounds__(256) void k_p23(
    const float* __restrict__ x, const float* __restrict__ ln_g,
    const float* __restrict__ ln_b, const float* __restrict__ bp,
    const float* __restrict__ po_part, const float* __restrict__ ne_part,
    const float* __restrict__ cnt_part,
    const float* __restrict__ M2t, const float* __restrict__ M3,
    float* __restrict__ out, float* __restrict__ mask_out)
{
  const int b = blockIdx.y;
  const int tid = threadIdx.x, lane = tid & 63, wave = tid >> 6;
  const int j = lane, q = wave;
  const float* xb = x + (size_t)b * NN * CC;

  __shared__ float s_flag;
  __shared__ float r_po[4][64], r_ne[4][64];
  __shared__ float y[3][64];
  __shared__ float A_l[3][64], V_l[3][64];

  if (q == 0) {
    float cs = cnt_part[b * P1B + j];
    for (int o = 1; o < 64; o <<= 1) cs += __shfl_xor(cs, o);
    if (j == 0) s_flag = (cs == 0.f) ? 1.f : 0.f;
  }

  float sp = 0.f, sn = 0.f;
  for (int k = q; k < P1B; k += 4) {
    const size_t base = ((size_t)b * P1B + k) * 64 + j;
    sp += po_part[base];
    sn += ne_part[base];
  }
  r_po[q][j] = sp; r_ne[q][j] = sn;
  __syncthreads();

  const bool flag = (s_flag != 0.f);
  if (q < 3) {
    const float po_s = r_po[0][j] + r_po[1][j] + r_po[2][j] + r_po[3][j];
    const float ne_s = r_ne[0][j] + r_ne[1][j] + r_ne[2][j] + r_ne[3][j];
    float v;
    if (q == 0)      v = xb[j];
    else if (q == 1) v = flag ? ne_s : po_s;  // count==0: mask->ones => row = ne_s
    else             v = flag ? 0.f : ne_s;
    float s = v;
    for (int o = 1; o < 64; o <<= 1) s += __shfl_xor(s, o);
    const float mu = s * (1.f / 64.f);
    const float d = v - mu;
    float s2 = d * d;
    for (int o = 1; o < 64; o <<= 1) s2 += __shfl_xor(s2, o);
    y[q][j] = d * rsqrtf(s2 * (1.f / 64.f) + 1e-5f) * ln_g[j] + ln_b[j];
  }
  __syncthreads();

  if (q < 3) {
    float sa = 0.f, sv = 0.f;
    for (int c = 0; c < 64; ++c) {
      const float yc = y[q][c];
      sa += yc * M2t[c * 64 + j];   // coalesced 256B per c, L2-hit
      sv += yc * M3 [c * 64 + j];
    }
    A_l[q][j] = 0.125f * sa;
    V_l[q][j] = sv;
  }
  __syncthreads();

  // per-lane register slices: 8 rows/wave, 8 floats per lane
  const int r = lane >> 3, c0 = (lane & 7) * 8;
  const f4 A0a = *reinterpret_cast<const f4*>(&A_l[0][c0]);
  const f4 A0b = *reinterpret_cast<const f4*>(&A_l[0][c0 + 4]);
  const f4 A1a = *reinterpret_cast<const f4*>(&A_l[1][c0]);
  const f4 A1b = *reinterpret_cast<const f4*>(&A_l[1][c0 + 4]);
  const f4 A2a = *reinterpret_cast<const f4*>(&A_l[2][c0]);
  const f4 A2b = *reinterpret_cast<const f4*>(&A_l[2][c0 + 4]);
  const f4 V0a = *reinterpret_cast<const f4*>(&V_l[0][c0]);
  const f4 V0b = *reinterpret_cast<const f4*>(&V_l[0][c0 + 4]);
  const f4 V1a = *reinterpret_cast<const f4*>(&V_l[1][c0]);
  const f4 V1b = *reinterpret_cast<const f4*>(&V_l[1][c0 + 4]);
  const f4 V2a = *reinterpret_cast<const f4*>(&V_l[2][c0]);
  const f4 V2b = *reinterpret_cast<const f4*>(&V_l[2][c0 + 4]);
  const f4 BPa = *reinterpret_cast<const f4*>(bp + c0);
  const f4 BPb = *reinterpret_cast<const f4*>(bp + c0 + 4);

  if (flag) {  // rare: count==0 -> mask all ones
    for (int i = blockIdx.x * 256 + tid; i < NT; i += P3B * 256)
      mask_out[(size_t)b * NT + i] = 1.f;
  }

  float* ob = out + (size_t)b * NN * CC;

  const int ngroups = (NN + 7) / 8;  // 2049
  for (int grp = blockIdx.x * 4 + wave; grp < ngroups; grp += P3B * 4) {
    const int n = grp * 8 + r;
    const bool valid = n < NN;
    f4 x0 = {0.f, 0.f, 0.f, 0.f}, x1 = {0.f, 0.f, 0.f, 0.f};
    if (valid) {
      x0 = *reinterpret_cast<const f4*>(xb + (size_t)n * CC + c0);
      x1 = *reinterpret_cast<const f4*>(xb + (size_t)n * CC + c0 + 4);
    }

    float p0 = x0.x * A0a.x + x0.y * A0a.y + x0.z * A0a.z + x0.w * A0a.w
             + x1.x * A0b.x + x1.y * A0b.y + x1.z * A0b.z + x1.w * A0b.w;
    float p1 = x0.x * A1a.x + x0.y * A1a.y + x0.z * A1a.z + x0.w * A1a.w
             + x1.x * A1b.x + x1.y * A1b.y + x1.z * A1b.z + x1.w * A1b.w;
    float p2 = x0.x * A2a.x + x0.y * A2a.y + x0.z * A2a.z + x0.w * A2a.w
             + x1.x * A2b.x + x1.y * A2b.y + x1.z * A2b.z + x1.w * A2b.w;
    #pragma unroll
    for (int o = 1; o < 8; o <<= 1) {
      p0 += __shfl_xor(p0, o);
      p1 += __shfl_xor(p1, o);
      p2 += __shfl_xor(p2, o);
    }
    const float mx = fmaxf(p0, fmaxf(p1, p2));
    float e0 = __expf(p0 - mx), e1 = __expf(p1 - mx), e2 = __expf(p2 - mx);
    const float inv = 1.f / (e0 + e1 + e2);
    e0 *= inv; e1 *= inv; e2 *= inv;

    f4 o0, o1;
    o0.x = BPa.x + e0 * V0a.x + e1 * V1a.x + e2 * V2a.x;
    o0.y = BPa.y + e0 * V0a.y + e1 * V1a.y + e2 * V2a.y;
    o0.z = BPa.z + e0 * V0a.z + e1 * V1a.z + e2 * V2a.z;
    o0.w = BPa.w + e0 * V0a.w + e1 * V1a.w + e2 * V2a.w;
    o1.x = BPb.x + e0 * V0b.x + e1 * V1b.x + e2 * V2b.x;
    o1.y = BPb.y + e0 * V0b.y + e1 * V1b.y + e2 * V2b.y;
    o1.z = BPb.z + e0 * V0b.z + e1 * V1b.z + e2 * V2b.z;
    o1.w = BPb.w + e0 * V0b.w + e1 * V1b.w + e2 * V2b.w;
    if (valid) {
      *reinterpret_cast<f4*>(ob + (size_t)n * CC + c0) = o0;
      *reinterpret_cast<f4*>(ob + (size_t)n * CC + c0 + 4) = o1;
    }
  }
}

extern "C" void kernel_launch(void* const* d_in, const int* in_sizes, int n_in,
                              void* d_out, int out_size, void* d_ws, size_t ws_size,
                              hipStream_t stream) {
  (void)in_sizes; (void)n_in; (void)out_size; (void)ws_size;
  const float* x    = (const float*)d_in[0];
  const float* Wq   = (const float*)d_in[1];
  const float* Wkv  = (const float*)d_in[2];
  const float* ln_g = (const float*)d_in[3];
  const float* ln_b = (const float*)d_in[4];
  const float* Wp   = (const float*)d_in[5];
  const float* bp   = (const float*)d_in[6];

  float* out      = (float*)d_out;                       // B*N*C
  float* mask_out = out + (size_t)BB * NN * CC;          // B*NT
  float* prob_out = mask_out + (size_t)BB * NT;          // B*NT

  float* ws        = (float*)d_ws;
  float* po_part   = ws;                                  // BB*P1B*64
  float* ne_part   = po_part + (size_t)BB * P1B * 64;     // BB*P1B*64
  float* cnt_part  = ne_part + (size_t)BB * P1B * 64;     // BB*P1B
  float* M2t       = cnt_part + BB * P1B;                 // 64*64
  float* M3        = M2t + 64 * 64;                       // 64*64

  k_p1<<<dim3(P1B, BB + 1), 256, 0, stream>>>(x, Wq, Wkv, Wp, mask_out, prob_out,
                                              po_part, ne_part, cnt_part, M2t, M3);
  k_p23<<<dim3(P3B, BB), 256, 0, stream>>>(x, ln_g, ln_b, bp,
                                           po_part, ne_part, cnt_part,
                                           M2t, M3, out, mask_out);
}

// Round 8
// 44.828 us; speedup vs baseline: 1.1150x; 1.1150x over previous
//
#include <hip/hip_runtime.h>
#include <cstddef>

#define BB 16
#define NN 16385
#define NT 16384
#define CC 64
#define P1B 64   // streaming blocks per batch in phase 1 (also = 64 weight-block count)
#define P3B 64   // blocks per batch in fused phase 2+3

typedef __attribute__((ext_vector_type(4))) float f4;

// ---- Kernel 1: phase1 streaming + (blockIdx.y==BB) weight-folding M2t/M3 ----
__global__ __launch_bounds__(256) void k_p1(
    const float* __restrict__ x, const float* __restrict__ Wq,
    const float* __restrict__ Wkv, const float* __restrict__ Wp,
    float* __restrict__ mask_out, float* __restrict__ prob_out,
    float* __restrict__ po_part, float* __restrict__ ne_part,
    float* __restrict__ cnt_part,
    float* __restrict__ M2t, float* __restrict__ M3)
{
  const int b = blockIdx.y, bx = blockIdx.x;
  const int tid = threadIdx.x, lane = tid & 63, wave = tid >> 6;

  if (b == BB) {
    // weight-only precompute: block bx = c in [0,64)
    // M2t[c][j] = sum_d Wq[j][d] * Wkv[c][d]        (A = 0.125 * y . M2t)
    // M3 [c][j] = sum_d Wkv[c][64+d] * Wp[d][j]     (V' = y . M3)
    const int c = bx, j = lane, q = wave;
    float s2 = 0.f, s3 = 0.f;
    #pragma unroll
    for (int dd = 0; dd < 16; ++dd) {
      const int d = q * 16 + dd;
      s2 += Wq[j * 64 + d] * Wkv[c * 128 + d];
      s3 += Wkv[c * 128 + 64 + d] * Wp[d * 64 + j];
    }
    __shared__ float t2[4][64], t3[4][64];
    t2[q][j] = s2; t3[q][j] = s3;
    __syncthreads();
    if (q == 0) {
      M2t[c * 64 + j] = t2[0][j] + t2[1][j] + t2[2][j] + t2[3][j];
      M3 [c * 64 + j] = t3[0][j] + t3[1][j] + t3[2][j] + t3[3][j];
    }
    return;
  }

  const int g = lane & 15, t = lane >> 4, c0 = g * 4;
  const float* xb = x + (size_t)b * NN * CC;
  const f4 wt4 = *reinterpret_cast<const f4*>(xb + c0);

  float apo[4] = {0.f, 0.f, 0.f, 0.f};
  float ane4[4] = {0.f, 0.f, 0.f, 0.f};
  float cntl = 0.f;

  for (int grp = bx * 4 + wave; grp < NT / 4; grp += P1B * 4) {
    const int n0 = grp * 4;
    const f4 xv = *reinterpret_cast<const f4*>(xb + (size_t)(1 + n0 + t) * CC + c0);
    float p = xv.x * wt4.x + xv.y * wt4.y + xv.z * wt4.z + xv.w * wt4.w;
    p += __shfl_xor(p, 1);
    p += __shfl_xor(p, 2);
    p += __shfl_xor(p, 4);
    p += __shfl_xor(p, 8);
    const bool m = p > 0.f;
    const float po = m ? p : 0.f;
    const float ne = m ? 0.f : p;
    apo[0] += po * xv.x; apo[1] += po * xv.y; apo[2] += po * xv.z; apo[3] += po * xv.w;
    ane4[0] += ne * xv.x; ane4[1] += ne * xv.y; ane4[2] += ne * xv.z; ane4[3] += ne * xv.w;
    if (g == 0) {
      const int nt = n0 + t;
      mask_out[(size_t)b * NT + nt] = m ? 1.f : 0.f;
      prob_out[(size_t)b * NT + nt] = 1.f / (1.f + __expf(-p));
      if (m) cntl += 1.f;
    }
  }

  #pragma unroll
  for (int i = 0; i < 4; ++i) {
    apo[i] += __shfl_xor(apo[i], 16); apo[i] += __shfl_xor(apo[i], 32);
    ane4[i] += __shfl_xor(ane4[i], 16); ane4[i] += __shfl_xor(ane4[i], 32);
  }
  cntl += __shfl_xor(cntl, 16);
  cntl += __shfl_xor(cntl, 32);

  __shared__ float s_po[4][64], s_ne[4][64], s_cnt[4];
  if (t == 0) {
    #pragma unroll
    for (int i = 0; i < 4; ++i) { s_po[wave][c0 + i] = apo[i]; s_ne[wave][c0 + i] = ane4[i]; }
  }
  if (lane == 0) s_cnt[wave] = cntl;
  __syncthreads();
  if (wave == 0) {
    const float sp = s_po[0][lane] + s_po[1][lane] + s_po[2][lane] + s_po[3][lane];
    const float sn = s_ne[0][lane] + s_ne[1][lane] + s_ne[2][lane] + s_ne[3][lane];
    const size_t base = ((size_t)b * P1B + bx) * 64 + lane;
    po_part[base] = sp;
    ne_part[base] = sn;
    if (lane == 0) cnt_part[b * P1B + bx] = s_cnt[0] + s_cnt[1] + s_cnt[2] + s_cnt[3];
  }
}

// ---- Kernel 2: fused phase2 (cheap vectorized preamble) + phase3 streaming ----
__global__ __launch_bounds__(256) void k_p23(
    const float* __restrict__ x, const float* __restrict__ ln_g,
    const float* __restrict__ ln_b, const float* __restrict__ bp,
    const float* __restrict__ po_part, const float* __restrict__ ne_part,
    const float* __restrict__ cnt_part,
    const float* __restrict__ M2t, const float* __restrict__ M3,
    float* __restrict__ out, float* __restrict__ mask_out)
{
  const int b = blockIdx.y;
  const int tid = threadIdx.x, lane = tid & 63, wave = tid >> 6;
  const int j = lane, q = wave;
  const int kq = tid >> 4, jg = tid & 15;  // 16 k-rows x 16 col-groups
  const float* xb = x + (size_t)b * NN * CC;

  __shared__ float s_flag;
  __shared__ f4 sm_po[16][16], sm_ne[16][16];
  __shared__ float po_s[64], ne_s[64];
  __shared__ float y[3][64];
  __shared__ float A_l[3][64], V_l[3][64];

  // vectorized partial reduce: thread (kq,jg) sums rows {kq,kq+16,kq+32,kq+48}, cols 4jg..4jg+3
  f4 sp4 = {0.f, 0.f, 0.f, 0.f}, sn4 = {0.f, 0.f, 0.f, 0.f};
  #pragma unroll
  for (int i = 0; i < 4; ++i) {
    const size_t base = ((size_t)b * P1B + kq + 16 * i) * 64 + jg * 4;
    const f4 a = *reinterpret_cast<const f4*>(po_part + base);
    const f4 c = *reinterpret_cast<const f4*>(ne_part + base);
    sp4 += a; sn4 += c;
  }
  sm_po[kq][jg] = sp4;
  sm_ne[kq][jg] = sn4;

  if (q == 3) {  // flag on the otherwise-idle wave
    float cs = cnt_part[b * P1B + j];
    for (int o = 1; o < 64; o <<= 1) cs += __shfl_xor(cs, o);
    if (j == 0) s_flag = (cs == 0.f) ? 1.f : 0.f;
  }
  __syncthreads();

  if (q == 0) {  // final per-column sums; lane j reads LDS word j (stride-1, no conflict)
    float s1 = 0.f, s2v = 0.f;
    #pragma unroll
    for (int k = 0; k < 16; ++k) {
      s1  += sm_po[k][j >> 2][j & 3];
      s2v += sm_ne[k][j >> 2][j & 3];
    }
    po_s[j] = s1; ne_s[j] = s2v;
  }
  __syncthreads();

  const bool flag = (s_flag != 0.f);
  if (q < 3) {
    float v;
    if (q == 0)      v = xb[j];
    else if (q == 1) v = flag ? ne_s[j] : po_s[j];  // count==0: mask->ones => row = ne_s
    else             v = flag ? 0.f : ne_s[j];
    float s = v;
    for (int o = 1; o < 64; o <<= 1) s += __shfl_xor(s, o);
    const float mu = s * (1.f / 64.f);
    const float d = v - mu;
    float s2 = d * d;
    for (int o = 1; o < 64; o <<= 1) s2 += __shfl_xor(s2, o);
    y[q][j] = d * rsqrtf(s2 * (1.f / 64.f) + 1e-5f) * ln_g[j] + ln_b[j];
  }
  __syncthreads();

  if (q < 3) {
    float sa = 0.f, sv = 0.f;
    #pragma unroll 8
    for (int c = 0; c < 64; ++c) {
      const float yc = y[q][c];
      sa += yc * M2t[c * 64 + j];   // coalesced 256B per c, L2-hit
      sv += yc * M3 [c * 64 + j];
    }
    A_l[q][j] = 0.125f * sa;
    V_l[q][j] = sv;
  }
  __syncthreads();

  // per-lane register slices: 8 rows/wave, 8 floats per lane
  const int r = lane >> 3, c0 = (lane & 7) * 8;
  const f4 A0a = *reinterpret_cast<const f4*>(&A_l[0][c0]);
  const f4 A0b = *reinterpret_cast<const f4*>(&A_l[0][c0 + 4]);
  const f4 A1a = *reinterpret_cast<const f4*>(&A_l[1][c0]);
  const f4 A1b = *reinterpret_cast<const f4*>(&A_l[1][c0 + 4]);
  const f4 A2a = *reinterpret_cast<const f4*>(&A_l[2][c0]);
  const f4 A2b = *reinterpret_cast<const f4*>(&A_l[2][c0 + 4]);
  const f4 V0a = *reinterpret_cast<const f4*>(&V_l[0][c0]);
  const f4 V0b = *reinterpret_cast<const f4*>(&V_l[0][c0 + 4]);
  const f4 V1a = *reinterpret_cast<const f4*>(&V_l[1][c0]);
  const f4 V1b = *reinterpret_cast<const f4*>(&V_l[1][c0 + 4]);
  const f4 V2a = *reinterpret_cast<const f4*>(&V_l[2][c0]);
  const f4 V2b = *reinterpret_cast<const f4*>(&V_l[2][c0 + 4]);
  const f4 BPa = *reinterpret_cast<const f4*>(bp + c0);
  const f4 BPb = *reinterpret_cast<const f4*>(bp + c0 + 4);

  if (flag) {  // rare: count==0 -> mask all ones (exactly 1 iter at P3B=64)
    for (int i = blockIdx.x * 256 + tid; i < NT; i += P3B * 256)
      mask_out[(size_t)b * NT + i] = 1.f;
  }

  float* ob = out + (size_t)b * NN * CC;

  const int ngroups = (NN + 7) / 8;  // 2049
  for (int grp = blockIdx.x * 4 + wave; grp < ngroups; grp += P3B * 4) {
    const int n = grp * 8 + r;
    const bool valid = n < NN;
    f4 x0 = {0.f, 0.f, 0.f, 0.f}, x1 = {0.f, 0.f, 0.f, 0.f};
    if (valid) {
      x0 = *reinterpret_cast<const f4*>(xb + (size_t)n * CC + c0);
      x1 = *reinterpret_cast<const f4*>(xb + (size_t)n * CC + c0 + 4);
    }

    float p0 = x0.x * A0a.x + x0.y * A0a.y + x0.z * A0a.z + x0.w * A0a.w
             + x1.x * A0b.x + x1.y * A0b.y + x1.z * A0b.z + x1.w * A0b.w;
    float p1 = x0.x * A1a.x + x0.y * A1a.y + x0.z * A1a.z + x0.w * A1a.w
             + x1.x * A1b.x + x1.y * A1b.y + x1.z * A1b.z + x1.w * A1b.w;
    float p2 = x0.x * A2a.x + x0.y * A2a.y + x0.z * A2a.z + x0.w * A2a.w
             + x1.x * A2b.x + x1.y * A2b.y + x1.z * A2b.z + x1.w * A2b.w;
    #pragma unroll
    for (int o = 1; o < 8; o <<= 1) {
      p0 += __shfl_xor(p0, o);
      p1 += __shfl_xor(p1, o);
      p2 += __shfl_xor(p2, o);
    }
    const float mx = fmaxf(p0, fmaxf(p1, p2));
    float e0 = __expf(p0 - mx), e1 = __expf(p1 - mx), e2 = __expf(p2 - mx);
    const float inv = 1.f / (e0 + e1 + e2);
    e0 *= inv; e1 *= inv; e2 *= inv;

    f4 o0, o1;
    o0.x = BPa.x + e0 * V0a.x + e1 * V1a.x + e2 * V2a.x;
    o0.y = BPa.y + e0 * V0a.y + e1 * V1a.y + e2 * V2a.y;
    o0.z = BPa.z + e0 * V0a.z + e1 * V1a.z + e2 * V2a.z;
    o0.w = BPa.w + e0 * V0a.w + e1 * V1a.w + e2 * V2a.w;
    o1.x = BPb.x + e0 * V0b.x + e1 * V1b.x + e2 * V2b.x;
    o1.y = BPb.y + e0 * V0b.y + e1 * V1b.y + e2 * V2b.y;
    o1.z = BPb.z + e0 * V0b.z + e1 * V1b.z + e2 * V2b.z;
    o1.w = BPb.w + e0 * V0b.w + e1 * V1b.w + e2 * V2b.w;
    if (valid) {
      *reinterpret_cast<f4*>(ob + (size_t)n * CC + c0) = o0;
      *reinterpret_cast<f4*>(ob + (size_t)n * CC + c0 + 4) = o1;
    }
  }
}

extern "C" void kernel_launch(void* const* d_in, const int* in_sizes, int n_in,
                              void* d_out, int out_size, void* d_ws, size_t ws_size,
                              hipStream_t stream) {
  (void)in_sizes; (void)n_in; (void)out_size; (void)ws_size;
  const float* x    = (const float*)d_in[0];
  const float* Wq   = (const float*)d_in[1];
  const float* Wkv  = (const float*)d_in[2];
  const float* ln_g = (const float*)d_in[3];
  const float* ln_b = (const float*)d_in[4];
  const float* Wp   = (const float*)d_in[5];
  const float* bp   = (const float*)d_in[6];

  float* out      = (float*)d_out;                       // B*N*C
  float* mask_out = out + (size_t)BB * NN * CC;          // B*NT
  float* prob_out = mask_out + (size_t)BB * NT;          // B*NT

  float* ws        = (float*)d_ws;
  float* po_part   = ws;                                  // BB*P1B*64
  float* ne_part   = po_part + (size_t)BB * P1B * 64;     // BB*P1B*64
  float* cnt_part  = ne_part + (size_t)BB * P1B * 64;     // BB*P1B
  float* M2t       = cnt_part + BB * P1B;                 // 64*64
  float* M3        = M2t + 64 * 64;                       // 64*64

  k_p1<<<dim3(P1B, BB + 1), 256, 0, stream>>>(x, Wq, Wkv, Wp, mask_out, prob_out,
                                              po_part, ne_part, cnt_part, M2t, M3);
  k_p23<<<dim3(P3B, BB), 256, 0, stream>>>(x, ln_g, ln_b, bp,
                                           po_part, ne_part, cnt_part,
                                           M2t, M3, out, mask_out);
}

// Round 10
// 44.524 us; speedup vs baseline: 1.1226x; 1.0068x over previous
//
#include <hip/hip_runtime.h>
#include <cstddef>

#define BB 16
#define NN 16385
#define NT 16384
#define CC 64
#define P1B 64   // streaming blocks per batch in phase 1 (also = 64 weight-block count)
#define P3B 64   // blocks per batch in fused phase 2+3

typedef __attribute__((ext_vector_type(4))) float f4;

// ---- Kernel 1: phase1 streaming (unroll x2) + (blockIdx.y==BB) weight-folding ----
__global__ __launch_bounds__(256) void k_p1(
    const float* __restrict__ x, const float* __restrict__ Wq,
    const float* __restrict__ Wkv, const float* __restrict__ Wp,
    float* __restrict__ mask_out, float* __restrict__ prob_out,
    float* __restrict__ po_part, float* __restrict__ ne_part,
    float* __restrict__ cnt_part,
    float* __restrict__ M2t, float* __restrict__ M3)
{
  const int b = blockIdx.y, bx = blockIdx.x;
  const int tid = threadIdx.x, lane = tid & 63, wave = tid >> 6;

  if (b == BB) {
    // weight-only precompute: block bx = c in [0,64)
    const int c = bx, j = lane, q = wave;
    float s2 = 0.f, s3 = 0.f;
    #pragma unroll
    for (int dd = 0; dd < 16; ++dd) {
      const int d = q * 16 + dd;
      s2 += Wq[j * 64 + d] * Wkv[c * 128 + d];
      s3 += Wkv[c * 128 + 64 + d] * Wp[d * 64 + j];
    }
    __shared__ float t2[4][64], t3[4][64];
    t2[q][j] = s2; t3[q][j] = s3;
    __syncthreads();
    if (q == 0) {
      M2t[c * 64 + j] = t2[0][j] + t2[1][j] + t2[2][j] + t2[3][j];
      M3 [c * 64 + j] = t3[0][j] + t3[1][j] + t3[2][j] + t3[3][j];
    }
    return;
  }

  const int g = lane & 15, t = lane >> 4, c0 = g * 4;
  const float* xb = x + (size_t)b * NN * CC;
  const f4 wt4 = *reinterpret_cast<const f4*>(xb + c0);

  float apo[4] = {0.f, 0.f, 0.f, 0.f};
  float ane4[4] = {0.f, 0.f, 0.f, 0.f};
  float cntl = 0.f;

  // 4096 groups, stride 256, unroll 2 -> 8 iterations, both groups always in range
  for (int grp = bx * 4 + wave; grp < NT / 4; grp += P1B * 8) {
    const int n0a = grp * 4;
    const int n0b = (grp + P1B * 4) * 4;
    const f4 xva = *reinterpret_cast<const f4*>(xb + (size_t)(1 + n0a + t) * CC + c0);
    const f4 xvb = *reinterpret_cast<const f4*>(xb + (size_t)(1 + n0b + t) * CC + c0);

    float pa = xva.x * wt4.x + xva.y * wt4.y + xva.z * wt4.z + xva.w * wt4.w;
    float pb = xvb.x * wt4.x + xvb.y * wt4.y + xvb.z * wt4.z + xvb.w * wt4.w;
    pa += __shfl_xor(pa, 1);  pb += __shfl_xor(pb, 1);
    pa += __shfl_xor(pa, 2);  pb += __shfl_xor(pb, 2);
    pa += __shfl_xor(pa, 4);  pb += __shfl_xor(pb, 4);
    pa += __shfl_xor(pa, 8);  pb += __shfl_xor(pb, 8);

    const bool ma = pa > 0.f, mb = pb > 0.f;
    const float poa = ma ? pa : 0.f, nea = ma ? 0.f : pa;
    const float pob = mb ? pb : 0.f, neb = mb ? 0.f : pb;
    apo[0] += poa * xva.x + pob * xvb.x;
    apo[1] += poa * xva.y + pob * xvb.y;
    apo[2] += poa * xva.z + pob * xvb.z;
    apo[3] += poa * xva.w + pob * xvb.w;
    ane4[0] += nea * xva.x + neb * xvb.x;
    ane4[1] += nea * xva.y + neb * xvb.y;
    ane4[2] += nea * xva.z + neb * xvb.z;
    ane4[3] += nea * xva.w + neb * xvb.w;
    if (g == 0) {
      const int nta = n0a + t, ntb = n0b + t;
      mask_out[(size_t)b * NT + nta] = ma ? 1.f : 0.f;
      prob_out[(size_t)b * NT + nta] = 1.f / (1.f + __expf(-pa));
      mask_out[(size_t)b * NT + ntb] = mb ? 1.f : 0.f;
      prob_out[(size_t)b * NT + ntb] = 1.f / (1.f + __expf(-pb));
      if (ma) cntl += 1.f;
      if (mb) cntl += 1.f;
    }
  }

  #pragma unroll
  for (int i = 0; i < 4; ++i) {
    apo[i] += __shfl_xor(apo[i], 16); apo[i] += __shfl_xor(apo[i], 32);
    ane4[i] += __shfl_xor(ane4[i], 16); ane4[i] += __shfl_xor(ane4[i], 32);
  }
  cntl += __shfl_xor(cntl, 16);
  cntl += __shfl_xor(cntl, 32);

  __shared__ float s_po[4][64], s_ne[4][64], s_cnt[4];
  if (t == 0) {
    #pragma unroll
    for (int i = 0; i < 4; ++i) { s_po[wave][c0 + i] = apo[i]; s_ne[wave][c0 + i] = ane4[i]; }
  }
  if (lane == 0) s_cnt[wave] = cntl;
  __syncthreads();
  if (wave == 0) {
    const float sp = s_po[0][lane] + s_po[1][lane] + s_po[2][lane] + s_po[3][lane];
    const float sn = s_ne[0][lane] + s_ne[1][lane] + s_ne[2][lane] + s_ne[3][lane];
    const size_t base = ((size_t)b * P1B + bx) * 64 + lane;
    po_part[base] = sp;
    ne_part[base] = sn;
    if (lane == 0) cnt_part[b * P1B + bx] = s_cnt[0] + s_cnt[1] + s_cnt[2] + s_cnt[3];
  }
}

// ---- Kernel 2: fused phase2 (vectorized preamble) + phase3 streaming (unroll x2) ----
__global__ __launch_bounds__(256, 4) void k_p23(
    const float* __restrict__ x, const float* __restrict__ ln_g,
    const float* __restrict__ ln_b, const float* __restrict__ bp,
    const float* __restrict__ po_part, const float* __restrict__ ne_part,
    const float* __restrict__ cnt_part,
    const float* __restrict__ M2t, const float* __restrict__ M3,
    float* __restrict__ out, float* __restrict__ mask_out)
{
  const int b = blockIdx.y;
  const int tid = threadIdx.x, lane = tid & 63, wave = tid >> 6;
  const int j = lane, q = wave;
  const int kq = tid >> 4, jg = tid & 15;
  const float* xb = x + (size_t)b * NN * CC;

  __shared__ float s_flag;
  __shared__ f4 sm_po[16][16], sm_ne[16][16];
  __shared__ float po_s[64], ne_s[64];
  __shared__ float y[3][64];
  __shared__ float A_l[3][64], V_l[3][64];

  f4 sp4 = {0.f, 0.f, 0.f, 0.f}, sn4 = {0.f, 0.f, 0.f, 0.f};
  #pragma unroll
  for (int i = 0; i < 4; ++i) {
    const size_t base = ((size_t)b * P1B + kq + 16 * i) * 64 + jg * 4;
    const f4 a = *reinterpret_cast<const f4*>(po_part + base);
    const f4 c = *reinterpret_cast<const f4*>(ne_part + base);
    sp4 += a; sn4 += c;
  }
  sm_po[kq][jg] = sp4;
  sm_ne[kq][jg] = sn4;

  if (q == 3) {
    float cs = cnt_part[b * P1B + j];
    for (int o = 1; o < 64; o <<= 1) cs += __shfl_xor(cs, o);
    if (j == 0) s_flag = (cs == 0.f) ? 1.f : 0.f;
  }
  __syncthreads();

  if (q == 0) {
    float s1 = 0.f, s2v = 0.f;
    #pragma unroll
    for (int k = 0; k < 16; ++k) {
      s1  += sm_po[k][j >> 2][j & 3];
      s2v += sm_ne[k][j >> 2][j & 3];
    }
    po_s[j] = s1; ne_s[j] = s2v;
  }
  __syncthreads();

  const bool flag = (s_flag != 0.f);
  if (q < 3) {
    float v;
    if (q == 0)      v = xb[j];
    else if (q == 1) v = flag ? ne_s[j] : po_s[j];  // count==0: mask->ones => row = ne_s
    else             v = flag ? 0.f : ne_s[j];
    float s = v;
    for (int o = 1; o < 64; o <<= 1) s += __shfl_xor(s, o);
    const float mu = s * (1.f / 64.f);
    const float d = v - mu;
    float s2 = d * d;
    for (int o = 1; o < 64; o <<= 1) s2 += __shfl_xor(s2, o);
    y[q][j] = d * rsqrtf(s2 * (1.f / 64.f) + 1e-5f) * ln_g[j] + ln_b[j];
  }
  __syncthreads();

  if (q < 3) {
    float sa = 0.f, sv = 0.f;
    #pragma unroll 8
    for (int c = 0; c < 64; ++c) {
      const float yc = y[q][c];
      sa += yc * M2t[c * 64 + j];
      sv += yc * M3 [c * 64 + j];
    }
    A_l[q][j] = 0.125f * sa;
    V_l[q][j] = sv;
  }
  __syncthreads();

  const int r = lane >> 3, c0 = (lane & 7) * 8;
  const f4 A0a = *reinterpret_cast<const f4*>(&A_l[0][c0]);
  const f4 A0b = *reinterpret_cast<const f4*>(&A_l[0][c0 + 4]);
  const f4 A1a = *reinterpret_cast<const f4*>(&A_l[1][c0]);
  const f4 A1b = *reinterpret_cast<const f4*>(&A_l[1][c0 + 4]);
  const f4 A2a = *reinterpret_cast<const f4*>(&A_l[2][c0]);
  const f4 A2b = *reinterpret_cast<const f4*>(&A_l[2][c0 + 4]);
  const f4 V0a = *reinterpret_cast<const f4*>(&V_l[0][c0]);
  const f4 V0b = *reinterpret_cast<const f4*>(&V_l[0][c0 + 4]);
  const f4 V1a = *reinterpret_cast<const f4*>(&V_l[1][c0]);
  const f4 V1b = *reinterpret_cast<const f4*>(&V_l[1][c0 + 4]);
  const f4 V2a = *reinterpret_cast<const f4*>(&V_l[2][c0]);
  const f4 V2b = *reinterpret_cast<const f4*>(&V_l[2][c0 + 4]);
  const f4 BPa = *reinterpret_cast<const f4*>(bp + c0);
  const f4 BPb = *reinterpret_cast<const f4*>(bp + c0 + 4);

  if (flag) {  // rare: count==0 -> mask all ones
    for (int i = blockIdx.x * 256 + tid; i < NT; i += P3B * 256)
      mask_out[(size_t)b * NT + i] = 1.f;
  }

  float* ob = out + (size_t)b * NN * CC;

  const int ngroups = (NN + 7) / 8;  // 2049
  for (int grpi = blockIdx.x * 4 + wave; grpi < ngroups; grpi += P3B * 8) {
    const int gB = grpi + P3B * 4;
    const int nA = grpi * 8 + r;
    const int nB = gB * 8 + r;
    const bool vA = nA < NN;
    const bool vB = (gB < ngroups) && (nB < NN);

    f4 xa0 = {0.f, 0.f, 0.f, 0.f}, xa1 = {0.f, 0.f, 0.f, 0.f};
    f4 xb0 = {0.f, 0.f, 0.f, 0.f}, xb1 = {0.f, 0.f, 0.f, 0.f};
    if (vA) {
      const f4* p = reinterpret_cast<const f4*>(xb + (size_t)nA * CC + c0);
      xa0 = p[0]; xa1 = p[1];
    }
    if (vB) {
      const f4* p = reinterpret_cast<const f4*>(xb + (size_t)nB * CC + c0);
      xb0 = p[0]; xb1 = p[1];
    }

    float pa0 = xa0.x * A0a.x + xa0.y * A0a.y + xa0.z * A0a.z + xa0.w * A0a.w
              + xa1.x * A0b.x + xa1.y * A0b.y + xa1.z * A0b.z + xa1.w * A0b.w;
    float pa1 = xa0.x * A1a.x + xa0.y * A1a.y + xa0.z * A1a.z + xa0.w * A1a.w
              + xa1.x * A1b.x + xa1.y * A1b.y + xa1.z * A1b.z + xa1.w * A1b.w;
    float pa2 = xa0.x * A2a.x + xa0.y * A2a.y + xa0.z * A2a.z + xa0.w * A2a.w
              + xa1.x * A2b.x + xa1.y * A2b.y + xa1.z * A2b.z + xa1.w * A2b.w;
    float pb0 = xb0.x * A0a.x + xb0.y * A0a.y + xb0.z * A0a.z + xb0.w * A0a.w
              + xb1.x * A0b.x + xb1.y * A0b.y + xb1.z * A0b.z + xb1.w * A0b.w;
    float pb1 = xb0.x * A1a.x + xb0.y * A1a.y + xb0.z * A1a.z + xb0.w * A1a.w
              + xb1.x * A1b.x + xb1.y * A1b.y + xb1.z * A1b.z + xb1.w * A1b.w;
    float pb2 = xb0.x * A2a.x + xb0.y * A2a.y + xb0.z * A2a.z + xb0.w * A2a.w
              + xb1.x * A2b.x + xb1.y * A2b.y + xb1.z * A2b.z + xb1.w * A2b.w;
    #pragma unroll
    for (int o = 1; o < 8; o <<= 1) {
      pa0 += __shfl_xor(pa0, o);  pb0 += __shfl_xor(pb0, o);
      pa1 += __shfl_xor(pa1, o);  pb1 += __shfl_xor(pb1, o);
      pa2 += __shfl_xor(pa2, o);  pb2 += __shfl_xor(pb2, o);
    }
    const float mxa = fmaxf(pa0, fmaxf(pa1, pa2));
    const float mxb = fmaxf(pb0, fmaxf(pb1, pb2));
    float ea0 = __expf(pa0 - mxa), ea1 = __expf(pa1 - mxa), ea2 = __expf(pa2 - mxa);
    float eb0 = __expf(pb0 - mxb), eb1 = __expf(pb1 - mxb), eb2 = __expf(pb2 - mxb);
    const float inva = 1.f / (ea0 + ea1 + ea2);
    const float invb = 1.f / (eb0 + eb1 + eb2);
    ea0 *= inva; ea1 *= inva; ea2 *= inva;
    eb0 *= invb; eb1 *= invb; eb2 *= invb;

    if (vA) {
      f4 o0, o1;
      o0.x = BPa.x + ea0 * V0a.x + ea1 * V1a.x + ea2 * V2a.x;
      o0.y = BPa.y + ea0 * V0a.y + ea1 * V1a.y + ea2 * V2a.y;
      o0.z = BPa.z + ea0 * V0a.z + ea1 * V1a.z + ea2 * V2a.z;
      o0.w = BPa.w + ea0 * V0a.w + ea1 * V1a.w + ea2 * V2a.w;
      o1.x = BPb.x + ea0 * V0b.x + ea1 * V1b.x + ea2 * V2b.x;
      o1.y = BPb.y + ea0 * V0b.y + ea1 * V1b.y + ea2 * V2b.y;
      o1.z = BPb.z + ea0 * V0b.z + ea1 * V1b.z + ea2 * V2b.z;
      o1.w = BPb.w + ea0 * V0b.w + ea1 * V1b.w + ea2 * V2b.w;
      f4* p = reinterpret_cast<f4*>(ob + (size_t)nA * CC + c0);
      p[0] = o0; p[1] = o1;
    }
    if (vB) {
      f4 o0, o1;
      o0.x = BPa.x + eb0 * V0a.x + eb1 * V1a.x + eb2 * V2a.x;
      o0.y = BPa.y + eb0 * V0a.y + eb1 * V1a.y + eb2 * V2a.y;
      o0.z = BPa.z + eb0 * V0a.z + eb1 * V1a.z + eb2 * V2a.z;
      o0.w = BPa.w + eb0 * V0a.w + eb1 * V1a.w + eb2 * V2a.w;
      o1.x = BPb.x + eb0 * V0b.x + eb1 * V1b.x + eb2 * V2b.x;
      o1.y = BPb.y + eb0 * V0b.y + eb1 * V1b.y + eb2 * V2b.y;
      o1.z = BPb.z + eb0 * V0b.z + eb1 * V1b.z + eb2 * V2b.z;
      o1.w = BPb.w + eb0 * V0b.w + eb1 * V1b.w + eb2 * V2b.w;
      f4* p = reinterpret_cast<f4*>(ob + (size_t)nB * CC + c0);
      p[0] = o0; p[1] = o1;
    }
  }
}

extern "C" void kernel_launch(void* const* d_in, const int* in_sizes, int n_in,
                              void* d_out, int out_size, void* d_ws, size_t ws_size,
                              hipStream_t stream) {
  (void)in_sizes; (void)n_in; (void)out_size; (void)ws_size;
  const float* x    = (const float*)d_in[0];
  const float* Wq   = (const float*)d_in[1];
  const float* Wkv  = (const float*)d_in[2];
  const float* ln_g = (const float*)d_in[3];
  const float* ln_b = (const float*)d_in[4];
  const float* Wp   = (const float*)d_in[5];
  const float* bp   = (const float*)d_in[6];

  float* out      = (float*)d_out;                       // B*N*C
  float* mask_out = out + (size_t)BB * NN * CC;          // B*NT
  float* prob_out = mask_out + (size_t)BB * NT;          // B*NT

  float* ws        = (float*)d_ws;
  float* po_part   = ws;                                  // BB*P1B*64
  float* ne_part   = po_part + (size_t)BB * P1B * 64;     // BB*P1B*64
  float* cnt_part  = ne_part + (size_t)BB * P1B * 64;     // BB*P1B
  float* M2t       = cnt_part + BB * P1B;                 // 64*64
  float* M3        = M2t + 64 * 64;                       // 64*64

  k_p1<<<dim3(P1B, BB + 1), 256, 0, stream>>>(x, Wq, Wkv, Wp, mask_out, prob_out,
                                              po_part, ne_part, cnt_part, M2t, M3);
  k_p23<<<dim3(P3B, BB), 256, 0, stream>>>(x, ln_g, ln_b, bp,
                                           po_part, ne_part, cnt_part,
                                           M2t, M3, out, mask_out);
}